// Round 14
// baseline (170.735 us; speedup 1.0000x reference)
//
#include <hip/hip_runtime.h>
#include <hip/hip_bf16.h>

// Problem constants (B,T,C,H) = (8,1024,768,12), D=64
#define Bb 8
#define Tt 1024
#define Cc 768
#define Hh 12
#define Dd 64
#define M_ROWS (Bb * Tt)      // 8192
#define QKV_N (3 * Cc)        // 2304

typedef __attribute__((ext_vector_type(8))) short s16x8;   // 8 x bf16
typedef __attribute__((ext_vector_type(4))) short s16x4;   // 4 x bf16
typedef __attribute__((ext_vector_type(4))) float f32x4;

#define AS1 __attribute__((address_space(1)))
#define AS3 __attribute__((address_space(3)))

static __device__ __forceinline__ short f2bf(float f) {
    union { float f; unsigned u; } v; v.f = f;
    unsigned r = (v.u + 0x7fffu + ((v.u >> 16) & 1u)) >> 16;  // RNE
    return (short)r;
}
// two f32 -> packed bf16x2 (TRUNCATION) in one v_perm_b32
static __device__ __forceinline__ unsigned pkt(float hi, float lo) {
    union { float f; unsigned u; } a, b; a.f = hi; b.f = lo;
    return __builtin_amdgcn_perm(a.u, b.u, 0x07060302u);
}

// ---------------------------------------------------------------------------
// Prep: fp32->bf16 casts + RoPE cos/sin table, one launch.
// wqkv rows are PERMUTED for q/k sections (sigma = row^0x30 for within-head
// quadrants 1,2): RoPE partners (i,i+32) become ADJACENT 16-col tiles.
// ---------------------------------------------------------------------------
static __device__ __forceinline__ void cast8(const float* __restrict__ in,
                                             short* __restrict__ out, int i) {
    const float4 a = ((const float4*)in)[i * 2];
    const float4 b = ((const float4*)in)[i * 2 + 1];
    s16x8 f;
    f[0] = f2bf(a.x); f[1] = f2bf(a.y); f[2] = f2bf(a.z); f[3] = f2bf(a.w);
    f[4] = f2bf(b.x); f[5] = f2bf(b.y); f[6] = f2bf(b.z); f[7] = f2bf(b.w);
    ((s16x8*)out)[i] = f;
}

#define S1 (M_ROWS * Cc / 8)   // 786432
#define S2 (QKV_N * Cc / 8)    // 221184
#define S3 (Cc * Cc / 8)       // 73728
#define SROPE (Tt * 32)        // 32768
#define PREP_THREADS (S1 + S2 + S3 + SROPE)  // 1114112 = 4352 * 256

__global__ __launch_bounds__(256) void prep_kernel(const float* __restrict__ x,
                                                   const float* __restrict__ wqkv,
                                                   const float* __restrict__ wproj,
                                                   short* __restrict__ xb,
                                                   short* __restrict__ wqkvb,
                                                   short* __restrict__ wprojb,
                                                   float2* __restrict__ cs) {
    int idx = blockIdx.x * blockDim.x + threadIdx.x;
    if (idx < S1) { cast8(x, xb, idx); return; }
    idx -= S1;
    if (idx < S2) {
        // permuted cast for wqkv: position-row n holds original row tau(n)
        int row = idx / 96;          // 768/8 = 96 chunks per row
        int c8  = idx - row * 96;
        int q2 = (row >> 4) & 3;
        int src = (row < 2 * Cc && (q2 == 1 || q2 == 2)) ? (row ^ 0x30) : row;
        const float4 a = ((const float4*)(wqkv + (size_t)src * Cc))[c8 * 2];
        const float4 b = ((const float4*)(wqkv + (size_t)src * Cc))[c8 * 2 + 1];
        s16x8 f;
        f[0] = f2bf(a.x); f[1] = f2bf(a.y); f[2] = f2bf(a.z); f[3] = f2bf(a.w);
        f[4] = f2bf(b.x); f[5] = f2bf(b.y); f[6] = f2bf(b.z); f[7] = f2bf(b.w);
        ((s16x8*)wqkvb)[idx] = f;
        return;
    }
    idx -= S2;
    if (idx < S3) { cast8(wproj, wprojb, idx); return; }
    idx -= S3;
    {
        int t = idx >> 5, i = idx & 31;
        float inv_freq = exp2f(-0.41524101186092037f * (float)i);  // log2(1e4)/32
        float fr = (float)t * inv_freq;
        float2 v; v.x = cosf(fr); v.y = sinf(fr);
        cs[idx] = v;
    }
}

// ---------------------------------------------------------------------------
// bf16 MFMA GEMM (NT): out[m][n] = sum_k A[m][k] * B[n][k]
// 128 x TN tile, BK=32, waves 2x2 (64 rows x TN/2 cols each).
// REGISTER-STAGED pipeline (flash-style) — fixes the barrier vmcnt(0) drain
// that stalled every global_load_lds variant (R5-R12, ~4400 cyc/iter):
//   per iter: barrier -> load_regs(kt+1) [global->VGPR, in flight] ->
//   24 MFMAs on LDS[buf] -> store_lds(buf^1) [s_waitcnt sits HERE, after
//   compute] -> next barrier's vmcnt(0) is already drained.
// Same XOR-swizzled LDS layout (conflict-free ds_read_b128; b128 writes).
// Grid = exact residency round: qkv TN=192 -> 768 blocks = 3/CU;
// proj TN=96 -> 512 blocks = 2/CU.  XCD bm-stripe swizzle.
// MODE 0: fp32 out.  MODE 1: bf16 out + fused RoPE epilogue (sigma-permuted
// wqkv -> rotation pairs are adjacent tiles); q scaled 0.125.
// ---------------------------------------------------------------------------
template <int MODE, int TN>
__global__ __launch_bounds__(256, 3) void gemm_nt_mfma(const short* __restrict__ A,
                                                       const short* __restrict__ B,
                                                       void* __restrict__ Cout,
                                                       const float2* __restrict__ cs,
                                                       int M, int N, int K, int nblocks) {
    __shared__ short As[2][128 * 32];
    __shared__ short Bs[2][TN * 32];
    constexpr int NTW = TN / 32;             // col-tiles per wave
    constexpr int BCH = TN * 4;              // B chunks per tile
    constexpr int BJ  = (BCH + 255) / 256;   // B chunk groups

    const int wave = threadIdx.x >> 6;
    const int lane = threadIdx.x & 63;
    const int l16  = lane & 15;
    const int quad = lane >> 4;
    const int wr = wave >> 1;
    const int wc = wave & 1;

    // XCD-aware swizzle (M/128 divisible by 8)
    const int mb8  = (M >> 7) >> 3;
    const int xcd  = blockIdx.x & 7;
    const int slot = blockIdx.x >> 3;
    const int bm = (xcd * mb8 + slot / nblocks) * 128;
    const int bn = (slot % nblocks) * TN;

    f32x4 acc[4][NTW] = {};
    s16x8 pra[2], prb[BJ];                   // prefetch registers

    auto load_regs = [&](int k0) {
#pragma unroll
        for (int j = 0; j < 2; j++) {        // A: 512 chunks
            const int D = j * 256 + wave * 64 + lane;
            const int G = D >> 3;
            const int s = (G << 3) | ((D & 7) ^ (G & 7));
            const int m = s >> 2, c4 = (s & 3) * 8;
            pra[j] = *(const s16x8*)(A + (size_t)(bm + m) * K + k0 + c4);
        }
#pragma unroll
        for (int j = 0; j < BJ; j++) {
            if (BCH % 256 == 0 || j * 256 + wave * 64 < BCH) {  // wave-uniform
                const int D = j * 256 + wave * 64 + lane;
                const int G = D >> 3;
                const int s = (G << 3) | ((D & 7) ^ (G & 7));
                const int m = s >> 2, c4 = (s & 3) * 8;
                prb[j] = *(const s16x8*)(B + (size_t)(bn + m) * K + k0 + c4);
            }
        }
    };
    auto store_lds = [&](int buf) {
#pragma unroll
        for (int j = 0; j < 2; j++) {
            const int D = j * 256 + wave * 64 + lane;
            *(s16x8*)&As[buf][D * 8] = pra[j];
        }
#pragma unroll
        for (int j = 0; j < BJ; j++) {
            if (BCH % 256 == 0 || j * 256 + wave * 64 < BCH) {
                const int D = j * 256 + wave * 64 + lane;
                *(s16x8*)&Bs[buf][D * 8] = prb[j];
            }
        }
    };

    const int nIter = K >> 5;   // K/32
    load_regs(0);
    store_lds(0);
    for (int kt = 0; kt < nIter; kt++) {
        const int buf = kt & 1;
        __syncthreads();                     // ds_writes of prev iter visible
        if (kt + 1 < nIter) load_regs((kt + 1) << 5);

        s16x8 af[4];
#pragma unroll
        for (int mt = 0; mt < 4; mt++) {
            const int m = wr * 64 + mt * 16 + l16;
            const int d = ((m & 1) * 4 + quad) ^ ((m >> 1) & 7);
            af[mt] = *(const s16x8*)&As[buf][(m >> 1) * 64 + d * 8];
        }
#pragma unroll
        for (int nt = 0; nt < NTW; nt++) {
            const int n = wc * (TN / 2) + nt * 16 + l16;
            const int d = ((n & 1) * 4 + quad) ^ ((n >> 1) & 7);
            s16x8 bf = *(const s16x8*)&Bs[buf][(n >> 1) * 64 + d * 8];
#pragma unroll
            for (int mt = 0; mt < 4; mt++)
                acc[mt][nt] = __builtin_amdgcn_mfma_f32_16x16x32_bf16(
                    af[mt], bf, acc[mt][nt], 0, 0, 0);
        }
        if (kt + 1 < nIter) store_lds(buf ^ 1);   // waits on prefetch loads only
    }

    if constexpr (MODE == 0) {
#pragma unroll
        for (int mt = 0; mt < 4; mt++)
#pragma unroll
            for (int r = 0; r < 4; r++) {
                const size_t row = bm + wr * 64 + mt * 16 + quad * 4 + r;
#pragma unroll
                for (int nt = 0; nt < NTW; nt++)
                    ((float*)Cout)[row * N + bn + wc * (TN / 2) + nt * 16 + l16] =
                        acc[mt][nt][r];
            }
    } else {
        const bool is_v = (bn >= 2 * Cc);
        if (is_v) {
#pragma unroll
            for (int mt = 0; mt < 4; mt++)
#pragma unroll
                for (int r = 0; r < 4; r++) {
                    const size_t row = bm + wr * 64 + mt * 16 + quad * 4 + r;
#pragma unroll
                    for (int nt = 0; nt < NTW; nt++)
                        ((short*)Cout)[row * N + bn + wc * (TN / 2) + nt * 16 + l16] =
                            f2bf(acc[mt][nt][r]);
                }
        } else {
            const float scale = (bn < Cc) ? 0.125f : 1.0f;  // q gets 1/sqrt(D)
#pragma unroll
            for (int mt = 0; mt < 4; mt++) {
#pragma unroll
                for (int r = 0; r < 4; r++) {
                    const int row = bm + wr * 64 + mt * 16 + quad * 4 + r;
                    const int t = row & (Tt - 1);
                    short* cp = (short*)Cout + (size_t)row * N + bn + wc * (TN / 2);
#pragma unroll
                    for (int p = 0; p < NTW; p += 2) {   // adjacent-tile pairs
                        const int g = wc * NTW + p;       // global col-tile (even)
                        const int i0 = ((g & 2) ? 16 : 0) + l16;
                        const float2 c0 = cs[t * 32 + i0];
                        const float x1 = acc[mt][p][r];
                        const float x2 = acc[mt][p + 1][r];
                        cp[p * 16 + l16]        = f2bf((x1 * c0.x + x2 * c0.y) * scale);
                        cp[(p + 1) * 16 + l16]  = f2bf((-x1 * c0.y + x2 * c0.x) * scale);
                    }
                }
            }
        }
    }
}

// ---------------------------------------------------------------------------
// Flash attention v3 (S^T formulation) — unchanged from R11/R12.
// ---------------------------------------------------------------------------
#define KSP 72
#define VSP 72

__global__ __launch_bounds__(256, 3) void flash_attn(const short* __restrict__ qkv,
                                                     short* __restrict__ y) {
    __shared__ short Ks[2][64 * KSP];
    __shared__ short Vs[2][64 * VSP];

    const int wave = threadIdx.x >> 6;
    const int lane = threadIdx.x & 63;
    const int l16  = lane & 15;
    const int quad = lane >> 4;

    const int pair = blockIdx.x / 96;     // 0..7
    const int bh   = blockIdx.x % 96;
    const int h = bh % Hh;
    const int b = bh / Hh;
    const int qa_blk = pair;
    const int qb_blk = 15 - pair;
    const int q0a = qa_blk * 64 + wave * 16;
    const int q0b = qb_blk * 64 + wave * 16;

    s16x8 qfa[2], qfb[2];
    {
        const short* qpa = qkv + (size_t)(b * Tt + q0a + l16) * QKV_N + h * Dd + quad * 8;
        const short* qpb = qkv + (size_t)(b * Tt + q0b + l16) * QKV_N + h * Dd + quad * 8;
        qfa[0] = *(const s16x8*)qpa;  qfa[1] = *(const s16x8*)(qpa + 32);
        qfb[0] = *(const s16x8*)qpb;  qfb[1] = *(const s16x8*)(qpb + 32);
    }

    f32x4 oa[4] = {}, ob[4] = {};
    float la = 0.f, lb = 0.f;

    const int krow = threadIdx.x >> 2;
    const int kd0  = (threadIdx.x & 3) * 16;
    const int key2 = (threadIdx.x & 31) * 2;
    const int dv0  = (threadIdx.x >> 5) * 8;

    s16x8 pk0, pk1, pv0, pv1;
    auto load_tile = [&](int kbase) {
        const short* kp = qkv + (size_t)(b * Tt + kbase + krow) * QKV_N + Cc + h * Dd + kd0;
        pk0 = *(const s16x8*)kp;
        pk1 = *(const s16x8*)(kp + 8);
        const short* vp = qkv + (size_t)(b * Tt + kbase + key2) * QKV_N + 2 * Cc + h * Dd + dv0;
        pv0 = *(const s16x8*)vp;
        pv1 = *(const s16x8*)(vp + QKV_N);
    };
    auto store_tile = [&](int buf) {
        *(s16x8*)&Ks[buf][krow * KSP + kd0]     = pk0;
        *(s16x8*)&Ks[buf][krow * KSP + kd0 + 8] = pk1;
#pragma unroll
        for (int j = 0; j < 8; j++) {
            ushort2 w; w.x = (unsigned short)pv0[j]; w.y = (unsigned short)pv1[j];
            *(ushort2*)&Vs[buf][(dv0 + j) * VSP + key2] = w;
        }
    };

    auto process_pair = [&](int buf, int kbase, bool mask_a) {
        short* pwb = &Ks[buf ^ 1][wave * 16 * KSP];
        short* pwa = &Vs[buf ^ 1][wave * 16 * VSP];
        f32x4 eb[4], ea[4];
#pragma unroll
        for (int g = 0; g < 4; g++) {
            s16x8 kf0 = *(const s16x8*)&Ks[buf][(g * 16 + l16) * KSP + quad * 8];
            s16x8 kf1 = *(const s16x8*)&Ks[buf][(g * 16 + l16) * KSP + 32 + quad * 8];
            f32x4 zb = {}, za = {};
            zb = __builtin_amdgcn_mfma_f32_16x16x32_bf16(kf0, qfb[0], zb, 0, 0, 0);
            zb = __builtin_amdgcn_mfma_f32_16x16x32_bf16(kf1, qfb[1], zb, 0, 0, 0);
            za = __builtin_amdgcn_mfma_f32_16x16x32_bf16(kf0, qfa[0], za, 0, 0, 0);
            za = __builtin_amdgcn_mfma_f32_16x16x32_bf16(kf1, qfa[1], za, 0, 0, 0);
            eb[g] = zb; ea[g] = za;
        }
        float rsb = 0.f, rsa = 0.f;
#pragma unroll
        for (int g = 0; g < 4; g++) {
#pragma unroll
            for (int r = 0; r < 4; r++) {
                float pb = __expf(eb[g][r]); rsb += pb; eb[g][r] = pb;
                float pa = __expf(ea[g][r]);
                if (mask_a) pa = (kbase + g * 16 + quad * 4 + r <= q0a + l16) ? pa : 0.0f;
                rsa += pa; ea[g][r] = pa;
            }
            uint2 ub, ua;
            ub.x = pkt(eb[g][1], eb[g][0]); ub.y = pkt(eb[g][3], eb[g][2]);
            ua.x = pkt(ea[g][1], ea[g][0]); ua.y = pkt(ea[g][3], ea[g][2]);
            *(uint2*)&pwb[l16 * KSP + g * 16 + quad * 4] = ub;
            *(uint2*)&pwa[l16 * VSP + g * 16 + quad * 4] = ua;
        }
        lb += rsb; la += rsa;
#pragma unroll
        for (int c = 0; c < 2; c++) {
            s16x8 pbb = *(const s16x8*)&pwb[l16 * KSP + c * 32 + quad * 8];
            s16x8 pba = *(const s16x8*)&pwa[l16 * VSP + c * 32 + quad * 8];
#pragma unroll
            for (int nc = 0; nc < 4; nc++) {
                s16x8 vb = *(const s16x8*)&Vs[buf][(nc * 16 + l16) * VSP + c * 32 + quad * 8];
                ob[nc] = __builtin_amdgcn_mfma_f32_16x16x32_bf16(vb, pbb, ob[nc], 0, 0, 0);
                oa[nc] = __builtin_amdgcn_mfma_f32_16x16x32_bf16(vb, pba, oa[nc], 0, 0, 0);
            }
        }
    };

    auto process_single = [&](int buf, int kbase, bool masked) {
        short* pw = &Ks[buf ^ 1][wave * 16 * KSP];
        f32x4 e[4];
#pragma unroll
        for (int g = 0; g < 4; g++) {
            s16x8 kf0 = *(const s16x8*)&Ks[buf][(g * 16 + l16) * KSP + quad * 8];
            s16x8 kf1 = *(const s16x8*)&Ks[buf][(g * 16 + l16) * KSP + 32 + quad * 8];
            f32x4 z = {};
            z = __builtin_amdgcn_mfma_f32_16x16x32_bf16(kf0, qfb[0], z, 0, 0, 0);
            z = __builtin_amdgcn_mfma_f32_16x16x32_bf16(kf1, qfb[1], z, 0, 0, 0);
            e[g] = z;
        }
        float rs = 0.f;
#pragma unroll
        for (int g = 0; g < 4; g++) {
#pragma unroll
            for (int r = 0; r < 4; r++) {
                float p = __expf(e[g][r]);
                if (masked) p = (kbase + g * 16 + quad * 4 + r <= q0b + l16) ? p : 0.0f;
                rs += p; e[g][r] = p;
            }
            uint2 u;
            u.x = pkt(e[g][1], e[g][0]); u.y = pkt(e[g][3], e[g][2]);
            *(uint2*)&pw[l16 * KSP + g * 16 + quad * 4] = u;
        }
        lb += rs;
#pragma unroll
        for (int c = 0; c < 2; c++) {
            s16x8 pb = *(const s16x8*)&pw[l16 * KSP + c * 32 + quad * 8];
#pragma unroll
            for (int nc = 0; nc < 4; nc++) {
                s16x8 vb = *(const s16x8*)&Vs[buf][(nc * 16 + l16) * VSP + c * 32 + quad * 8];
                ob[nc] = __builtin_amdgcn_mfma_f32_16x16x32_bf16(vb, pb, ob[nc], 0, 0, 0);
            }
        }
    };

    load_tile(0);
    store_tile(0);
    for (int kt = 0; kt <= qb_blk; kt++) {
        __syncthreads();
        const int nb = (kt < qb_blk) ? (kt + 1) * 64 : qb_blk * 64;
        load_tile(nb);
        const int buf = kt & 1;
        const int kbase = kt * 64;
        if (kt <= qa_blk)
            process_pair(buf, kbase, kt == qa_blk);
        else
            process_single(buf, kbase, kt == qb_blk);
        store_tile(buf ^ 1);
    }

    float sa = la; sa += __shfl_xor(sa, 16, 64); sa += __shfl_xor(sa, 32, 64);
    float sb = lb; sb += __shfl_xor(sb, 16, 64); sb += __shfl_xor(sb, 32, 64);
    const float inva = 1.0f / sa;
    const float invb = 1.0f / sb;
    short* ypa = y + (size_t)(b * Tt + q0a + l16) * Cc + h * Dd + quad * 4;
    short* ypb = y + (size_t)(b * Tt + q0b + l16) * Cc + h * Dd + quad * 4;
#pragma unroll
    for (int nc = 0; nc < 4; nc++) {
        s16x4 va, vb2;
#pragma unroll
        for (int r = 0; r < 4; r++) {
            va[r]  = f2bf(oa[nc][r] * inva);
            vb2[r] = f2bf(ob[nc][r] * invb);
        }
        *(s16x4*)&ypa[nc * 16] = va;
        *(s16x4*)&ypb[nc * 16] = vb2;
    }
}

// ---------------------------------------------------------------------------
extern "C" void kernel_launch(void* const* d_in, const int* in_sizes, int n_in,
                              void* d_out, int out_size, void* d_ws, size_t ws_size,
                              hipStream_t stream) {
    const float* x      = (const float*)d_in[0];
    const float* w_qkv  = (const float*)d_in[1];
    const float* w_proj = (const float*)d_in[2];
    float* out = (float*)d_out;

    float2* cs    = (float2*)d_ws;                         // 1024*32 float2
    short* xb     = (short*)(cs + Tt * 32);                // 8192x768
    short* wqkvb  = xb + (size_t)M_ROWS * Cc;              // 2304x768 (sigma-permuted q/k rows)
    short* wprojb = wqkvb + (size_t)QKV_N * Cc;            // 768x768
    short* qkvb   = wprojb + (size_t)Cc * Cc;              // 8192x2304
    short* yb     = qkvb + (size_t)M_ROWS * QKV_N;         // 8192x768

    prep_kernel<<<PREP_THREADS / 256, 256, 0, stream>>>(
        x, w_qkv, w_proj, xb, wqkvb, wprojb, cs);

    // qkv = x @ w_qkv.T with fused RoPE + q-scale (bf16 out): 768 blocks = 3/CU
    gemm_nt_mfma<1, 192><<<768, 256, 0, stream>>>(
        xb, wqkvb, qkvb, cs, M_ROWS, QKV_N, Cc, QKV_N / 192);

    flash_attn<<<96 * 8, 256, 0, stream>>>(qkvb, yb);

    // out = y @ w_proj.T (fp32 out): 512 blocks = 2/CU exact
    gemm_nt_mfma<0, 96><<<512, 256, 0, stream>>>(
        yb, wprojb, out, nullptr, M_ROWS, Cc, Cc, Cc / 96);
}